// Round 7
// baseline (437.792 us; speedup 1.0000x reference)
//
#include <hip/hip_runtime.h>

#define T_DIM 512
#define C_DIM 48
#define BPS   48          // bp row stride; lanes 48-63 spill into next row (overwritten later / never read)
#define CH    4           // global-prefetch chunk (distance ~4-8 steps)
#define NBLK  2048        // persistent single-wave blocks (extra blocks exit instantly)

#if __has_builtin(__builtin_amdgcn_readlane)
#define READLANE_I(v, l) __builtin_amdgcn_readlane((v), (l))
#else
#define READLANE_I(v, l) __shfl((v), (l), 64)
#endif

// Broadcast lane `lane`'s float to the whole wave (wave-uniform result).
__device__ __forceinline__ float bcast_lane(float v, int lane) {
    return __uint_as_float((unsigned)READLANE_I((int)__float_as_uint(v), lane));
}

__device__ __forceinline__ unsigned umin_(unsigned a, unsigned b) { return a < b ? a : b; }

// d == +0 (max-tier) -> i ; d < 0 -> 0xFFFFFFC0 | i (huge).
__device__ __forceinline__ unsigned enc_idx(float d, unsigned i) {
    unsigned s = (unsigned)(((int)__float_as_int(d)) >> 31);   // 0 or 0xFFFFFFFF
    return (s & 0xFFFFFFC0u) | i;
}

#define MAX3(a, b, c) fmaxf(fmaxf((a), (b)), (c))
#define EMIN3(I_) umin_(umin_(enc_idx(cv[(I_)] - m_, (I_)),                 \
                              enc_idx(cv[(I_) + 1] - m_, (I_) + 1)),        \
                        enc_idx(cv[(I_) + 2] - m_, (I_) + 2))

// One Viterbi step (proven R6 structure): hazard-free VALU trees, exact
// jnp.argmax first-occurrence tie-break, readlane re-broadcast.
#define VSTEP(T_, PV_) do {                                                  \
    float cv[C_DIM];                                                         \
    _Pragma("unroll")                                                        \
    for (int i_ = 0; i_ < C_DIM; ++i_) cv[i_] = sreg[i_] + tc[i_];           \
    float A0  = MAX3(cv[0],  cv[1],  cv[2]);                                 \
    float A1  = MAX3(cv[3],  cv[4],  cv[5]);                                 \
    float A2  = MAX3(cv[6],  cv[7],  cv[8]);                                 \
    float A3  = MAX3(cv[9],  cv[10], cv[11]);                                \
    float A4  = MAX3(cv[12], cv[13], cv[14]);                                \
    float A5  = MAX3(cv[15], cv[16], cv[17]);                                \
    float A6  = MAX3(cv[18], cv[19], cv[20]);                                \
    float A7  = MAX3(cv[21], cv[22], cv[23]);                                \
    float A8  = MAX3(cv[24], cv[25], cv[26]);                                \
    float A9  = MAX3(cv[27], cv[28], cv[29]);                                \
    float A10 = MAX3(cv[30], cv[31], cv[32]);                                \
    float A11 = MAX3(cv[33], cv[34], cv[35]);                                \
    float A12 = MAX3(cv[36], cv[37], cv[38]);                                \
    float A13 = MAX3(cv[39], cv[40], cv[41]);                                \
    float A14 = MAX3(cv[42], cv[43], cv[44]);                                \
    float A15 = MAX3(cv[45], cv[46], cv[47]);                                \
    float B0 = MAX3(A0,  A1,  A2);                                           \
    float B1 = MAX3(A3,  A4,  A5);                                           \
    float B2 = MAX3(A6,  A7,  A8);                                           \
    float B3 = MAX3(A9,  A10, A11);                                          \
    float B4 = MAX3(A12, A13, A14);                                          \
    float Cx0 = MAX3(B0, B1, B2);                                            \
    float Cx1 = MAX3(B3, B4, A15);                                           \
    const float m_ = fmaxf(Cx0, Cx1);                                        \
    unsigned U0  = EMIN3(0);   unsigned U1  = EMIN3(3);                      \
    unsigned U2  = EMIN3(6);   unsigned U3  = EMIN3(9);                      \
    unsigned U4  = EMIN3(12);  unsigned U5  = EMIN3(15);                     \
    unsigned U6  = EMIN3(18);  unsigned U7  = EMIN3(21);                     \
    unsigned U8  = EMIN3(24);  unsigned U9  = EMIN3(27);                     \
    unsigned U10 = EMIN3(30);  unsigned U11 = EMIN3(33);                     \
    unsigned U12 = EMIN3(36);  unsigned U13 = EMIN3(39);                     \
    unsigned U14 = EMIN3(42);  unsigned U15 = EMIN3(45);                     \
    unsigned V0 = umin_(umin_(U0,  U1),  U2);                                \
    unsigned V1 = umin_(umin_(U3,  U4),  U5);                                \
    unsigned V2 = umin_(umin_(U6,  U7),  U8);                                \
    unsigned V3 = umin_(umin_(U9,  U10), U11);                               \
    unsigned V4 = umin_(umin_(U12, U13), U14);                               \
    unsigned W0 = umin_(umin_(V0, V1), V2);                                  \
    unsigned W1 = umin_(umin_(V3, V4), U15);                                 \
    const unsigned wi_ = umin_(W0, W1);                                      \
    const float ns_ = m_ + (PV_);                                            \
    bp[(T_) * BPS + tid] = (unsigned char)wi_;  /* all 64 lanes; spill ok */ \
    _Pragma("unroll")                                                        \
    for (int i_ = 0; i_ < C_DIM; ++i_) sreg[i_] = bcast_lane(ns_, i_);       \
} while (0)

// Counting sort of batch ids by L descending (LPT order). One block.
__global__ __launch_bounds__(512) void sort_by_len(
    const int* __restrict__ seqlen, int* __restrict__ order, int B)
{
    __shared__ int hist[T_DIM];
    __shared__ int start[T_DIM];
    const int tid = threadIdx.x;
    hist[tid] = 0;
    __syncthreads();
    for (int b = tid; b < B; b += 512) atomicAdd(&hist[seqlen[b]], 1);  // L in [1,511]
    __syncthreads();
    if (tid == 0) {
        int acc = 0;
        for (int L = T_DIM - 1; L >= 0; --L) { start[L] = acc; acc += hist[L]; }
    }
    __syncthreads();
    for (int b = tid; b < B; b += 512) {
        int pos = atomicAdd(&start[seqlen[b]], 1);
        order[pos] = b;
    }
}

__global__ __launch_bounds__(64) void crf_viterbi(
    const float* __restrict__ pot,     // [B][T][C]
    const int*   __restrict__ seqlen,  // [B][1]
    const float* __restrict__ trans,   // [C][C]
    float*       __restrict__ out,     // [B][T][C] one-hot f32
    const int*   __restrict__ order,   // [B] batch ids, L descending
    int*         __restrict__ ctr,     // global work counter (zeroed each launch)
    int B)
{
    const int tid = threadIdx.x;
    const int jj  = (tid < C_DIM) ? tid : (C_DIM - 1);  // clamped for safe loads

    __shared__ unsigned char bp[T_DIM * BPS];            // 24.6 KB
    __shared__ __align__(4) unsigned char tags[T_DIM];
    __shared__ int k_sh;

    // transitions column j in registers (clamped col for lanes >= 48) — loop-invariant
    float tc[C_DIM];
#pragma unroll
    for (int i = 0; i < C_DIM; ++i) tc[i] = trans[i * C_DIM + jj];

    for (;;) {
        if (tid == 0) k_sh = atomicAdd(ctr, 1);
        __syncthreads();
        const int k = k_sh;
        __syncthreads();
        if (k >= B) break;                // wave-uniform
        const int b = order[k];

        const float* potb = pot + (size_t)b * (T_DIM * C_DIM);
        const int L   = seqlen[b];        // in [1, 511]
        const int thi = L - 1;

        // init: score vector (wave-uniform) = potentials[:,0]
        float sreg[C_DIM];
        {
            const float s0 = potb[jj];
#pragma unroll
            for (int i = 0; i < C_DIM; ++i) sreg[i] = bcast_lane(s0, i);
        }

        const float* pp = potb + jj;

        // software-pipelined forward loop: prefetch chunk CH ahead (clamped rows)
        float pb[CH];
#pragma unroll
        for (int kk = 0; kk < CH; ++kk) {
            int tt = 1 + kk; if (tt > T_DIM - 1) tt = T_DIM - 1;
            pb[kk] = pp[tt * C_DIM];
        }
        for (int t0 = 1; t0 < L; t0 += CH) {
            float nb[CH];
#pragma unroll
            for (int kk = 0; kk < CH; ++kk) {
                int tt = t0 + CH + kk; if (tt > T_DIM - 1) tt = T_DIM - 1;
                nb[kk] = pp[tt * C_DIM];
            }
#pragma unroll
            for (int kk = 0; kk < CH; ++kk) {
                const int t = t0 + kk;
                if (t >= L) break;        // wave-uniform branch
                VSTEP(t, pb[kk]);
            }
#pragma unroll
            for (int kk = 0; kk < CH; ++kk) pb[kk] = nb[kk];
        }
        __syncthreads();   // phase boundary (single wave; cheap)

        // last_tag = argmax over final scores (wave-uniform values)
        float bv = sreg[0];
        int   bi = 0;
#pragma unroll
        for (int i = 1; i < C_DIM; ++i) {
            if (sreg[i] > bv) { bv = sreg[i]; bi = i; }
        }
        const int last_tag = __builtin_amdgcn_readfirstlane(bi);

        // prefill tags[t] = last_tag for t in [L, T)
        for (int t = L + tid; t < T_DIM; t += 64) tags[t] = (unsigned char)last_tag;

        // serial backtrace: for t = thi..1: tags[t] = y; y = bp[t][y]; then tags[0] = y
        int y = last_tag;  // wave-uniform
        for (int c0 = (thi >> 6) << 6; c0 >= 0; c0 -= 64) {
            int row[64];   // row[kk] holds bp[c0+kk][jj] in lane jj
#pragma unroll
            for (int kk = 0; kk < 64; ++kk) row[kk] = bp[(c0 + kk) * BPS + jj];

            int vacc = 0;
#pragma unroll
            for (int kk = 63; kk >= 0; --kk) {
                const int t = c0 + kk;
                vacc = (tid == kk) ? y : vacc;                    // tags[t] = y (lane kk)
                const int ynew = READLANE_I(row[kk], y);
                if ((unsigned)(t - 1) < (unsigned)thi) y = ynew;  // update only for t in [1, thi]
            }
            const int tk = c0 + tid;
            if (tk <= thi) tags[tk] = (unsigned char)(vacc & 0xff);
        }
        __syncthreads();   // phase boundary

        // emit one-hot: 4 rows (t) per iteration, 48 lanes x float4 coalesced
        if (tid < C_DIM) {
            const int r = tid / 12;          // row-in-group 0..3
            const int q = tid - r * 12;      // float4 slot 0..11
            const int cbase = q * 4;
            float* ob = out + (size_t)b * (T_DIM * C_DIM);
            for (int t0 = 0; t0 < T_DIM; t0 += 4) {
                const unsigned int tg4 = *(const unsigned int*)&tags[t0];
                const int mytag = (int)((tg4 >> (r * 8)) & 0xffu);
                float4 v;
                v.x = (cbase + 0 == mytag) ? 1.0f : 0.0f;
                v.y = (cbase + 1 == mytag) ? 1.0f : 0.0f;
                v.z = (cbase + 2 == mytag) ? 1.0f : 0.0f;
                v.w = (cbase + 3 == mytag) ? 1.0f : 0.0f;
                *(float4*)(ob + (size_t)(t0 + r) * C_DIM + cbase) = v;
            }
        }
        __syncthreads();   // LDS reuse boundary before next grab
    }
}

extern "C" void kernel_launch(void* const* d_in, const int* in_sizes, int n_in,
                              void* d_out, int out_size, void* d_ws, size_t ws_size,
                              hipStream_t stream) {
    const float* pot    = (const float*)d_in[0];
    const int*   sl     = (const int*)d_in[1];
    const float* trans  = (const float*)d_in[2];
    float*       out    = (float*)d_out;
    const int B = in_sizes[1];  // sequence_lengths has B elements

    int* ctr   = (int*)d_ws;           // 16 B reserved
    int* order = (int*)d_ws + 4;       // B ints

    hipMemsetAsync(ctr, 0, 16, stream);                       // zero the work counter
    sort_by_len<<<1, 512, 0, stream>>>(sl, order, B);         // LPT order (L desc)
    crf_viterbi<<<NBLK, 64, 0, stream>>>(pot, sl, trans, out, order, ctr, B);
}

// Round 8
// 396.743 us; speedup vs baseline: 1.1035x; 1.1035x over previous
//
#include <hip/hip_runtime.h>

#define T_DIM 512
#define C_DIM 48
#define BPS   64          // bp row stride (padded to 64 so all lanes store)
#define CH    4           // global-prefetch chunk (distance ~4-8 steps)

#if __has_builtin(__builtin_amdgcn_readlane)
#define READLANE_I(v, l) __builtin_amdgcn_readlane((v), (l))
#else
#define READLANE_I(v, l) __shfl((v), (l), 64)
#endif

// Broadcast lane `lane`'s float to the whole wave (wave-uniform result).
__device__ __forceinline__ float bcast_lane(float v, int lane) {
    return __uint_as_float((unsigned)READLANE_I((int)__float_as_uint(v), lane));
}

__device__ __forceinline__ unsigned umin_(unsigned a, unsigned b) { return a < b ? a : b; }

// d = cv_i - m is +0.0 (bits 0x00000000) iff cv_i == m (max-tier), else
// strictly negative (sign bit set => bits >= 0x80000000). So bits(d)|i is
// exactly i for max-tier entries and >= 0x80000000 otherwise; umin over all i
// returns the LOWEST max-tier index == jnp.argmax first-occurrence. 1 op.
__device__ __forceinline__ unsigned enc_idx(float d, unsigned i) {
    return __float_as_uint(d) | i;
}

#define MAX3(a, b, c) fmaxf(fmaxf((a), (b)), (c))
#define EMIN3(I_) umin_(umin_(enc_idx(cv[(I_)] - m_, (I_)),                 \
                              enc_idx(cv[(I_) + 1] - m_, (I_) + 1)),        \
                        enc_idx(cv[(I_) + 2] - m_, (I_) + 2))

// One Viterbi step. Scores wave-uniform in sreg[48]. Lane j computes
// argmax_i(sreg[i] + tc[i]) via hazard-free VALU trees:
//   value  : v_max3_f32 tree (exact max, no scalar-reg writes)
//   argmax : bits(cv_i - m) | i, v_min3_u32 tree (1-op encode)
// bp -> LDS (write-only, off critical path); new score re-broadcast via
// readlane (the only scalar writes in the loop).
#define VSTEP(T_, PV_) do {                                                  \
    float cv[C_DIM];                                                         \
    _Pragma("unroll")                                                        \
    for (int i_ = 0; i_ < C_DIM; ++i_) cv[i_] = sreg[i_] + tc[i_];           \
    float A0  = MAX3(cv[0],  cv[1],  cv[2]);                                 \
    float A1  = MAX3(cv[3],  cv[4],  cv[5]);                                 \
    float A2  = MAX3(cv[6],  cv[7],  cv[8]);                                 \
    float A3  = MAX3(cv[9],  cv[10], cv[11]);                                \
    float A4  = MAX3(cv[12], cv[13], cv[14]);                                \
    float A5  = MAX3(cv[15], cv[16], cv[17]);                                \
    float A6  = MAX3(cv[18], cv[19], cv[20]);                                \
    float A7  = MAX3(cv[21], cv[22], cv[23]);                                \
    float A8  = MAX3(cv[24], cv[25], cv[26]);                                \
    float A9  = MAX3(cv[27], cv[28], cv[29]);                                \
    float A10 = MAX3(cv[30], cv[31], cv[32]);                                \
    float A11 = MAX3(cv[33], cv[34], cv[35]);                                \
    float A12 = MAX3(cv[36], cv[37], cv[38]);                                \
    float A13 = MAX3(cv[39], cv[40], cv[41]);                                \
    float A14 = MAX3(cv[42], cv[43], cv[44]);                                \
    float A15 = MAX3(cv[45], cv[46], cv[47]);                                \
    float B0 = MAX3(A0,  A1,  A2);                                           \
    float B1 = MAX3(A3,  A4,  A5);                                           \
    float B2 = MAX3(A6,  A7,  A8);                                           \
    float B3 = MAX3(A9,  A10, A11);                                          \
    float B4 = MAX3(A12, A13, A14);                                          \
    float Cx0 = MAX3(B0, B1, B2);                                            \
    float Cx1 = MAX3(B3, B4, A15);                                           \
    const float m_ = fmaxf(Cx0, Cx1);                                        \
    unsigned U0  = EMIN3(0);   unsigned U1  = EMIN3(3);                      \
    unsigned U2  = EMIN3(6);   unsigned U3  = EMIN3(9);                      \
    unsigned U4  = EMIN3(12);  unsigned U5  = EMIN3(15);                     \
    unsigned U6  = EMIN3(18);  unsigned U7  = EMIN3(21);                     \
    unsigned U8  = EMIN3(24);  unsigned U9  = EMIN3(27);                     \
    unsigned U10 = EMIN3(30);  unsigned U11 = EMIN3(33);                     \
    unsigned U12 = EMIN3(36);  unsigned U13 = EMIN3(39);                     \
    unsigned U14 = EMIN3(42);  unsigned U15 = EMIN3(45);                     \
    unsigned V0 = umin_(umin_(U0,  U1),  U2);                                \
    unsigned V1 = umin_(umin_(U3,  U4),  U5);                                \
    unsigned V2 = umin_(umin_(U6,  U7),  U8);                                \
    unsigned V3 = umin_(umin_(U9,  U10), U11);                               \
    unsigned V4 = umin_(umin_(U12, U13), U14);                               \
    unsigned W0 = umin_(umin_(V0, V1), V2);                                  \
    unsigned W1 = umin_(umin_(V3, V4), U15);                                 \
    const unsigned wi_ = umin_(W0, W1) & 63u;                                \
    const float ns_ = m_ + (PV_);                                            \
    bp[(T_) * BPS + tid] = (unsigned char)wi_;  /* all 64 lanes; pad ok */   \
    _Pragma("unroll")                                                        \
    for (int i_ = 0; i_ < C_DIM; ++i_) sreg[i_] = bcast_lane(ns_, i_);       \
} while (0)

__global__ __launch_bounds__(64) void crf_viterbi(
    const float* __restrict__ pot,     // [B][T][C]
    const int*   __restrict__ seqlen,  // [B][1]
    const float* __restrict__ trans,   // [C][C]
    float*       __restrict__ out)     // [B][T][C] one-hot f32
{
    const int b   = blockIdx.x;
    const int tid = threadIdx.x;
    const int jj  = (tid < C_DIM) ? tid : (C_DIM - 1);  // clamped for safe loads

    __shared__ unsigned char bp[T_DIM * BPS];            // rows 1..L-1 used
    __shared__ __align__(4) unsigned char tags[T_DIM];

    const float* potb = pot + (size_t)b * (T_DIM * C_DIM);
    const int L   = seqlen[b];          // in [1, 511]
    const int thi = L - 1;

    // transitions column j in registers (clamped col for lanes >= 48)
    float tc[C_DIM];
#pragma unroll
    for (int i = 0; i < C_DIM; ++i) tc[i] = trans[i * C_DIM + jj];

    // init: score vector (wave-uniform) = potentials[:,0]
    float sreg[C_DIM];
    {
        const float s0 = potb[jj];
#pragma unroll
        for (int i = 0; i < C_DIM; ++i) sreg[i] = bcast_lane(s0, i);
    }

    const float* pp = potb + jj;

    // software-pipelined forward loop: prefetch chunk CH ahead (clamped rows)
    float pb[CH];
#pragma unroll
    for (int k = 0; k < CH; ++k) {
        int tt = 1 + k; if (tt > T_DIM - 1) tt = T_DIM - 1;
        pb[k] = pp[tt * C_DIM];
    }
    for (int t0 = 1; t0 < L; t0 += CH) {
        float nb[CH];
#pragma unroll
        for (int k = 0; k < CH; ++k) {
            int tt = t0 + CH + k; if (tt > T_DIM - 1) tt = T_DIM - 1;
            nb[k] = pp[tt * C_DIM];
        }
#pragma unroll
        for (int k = 0; k < CH; ++k) {
            const int t = t0 + k;
            if (t >= L) break;           // wave-uniform branch
            VSTEP(t, pb[k]);
        }
#pragma unroll
        for (int k = 0; k < CH; ++k) pb[k] = nb[k];
    }
    __syncthreads();   // phase boundary (single wave; cheap)

    // last_tag = argmax over final scores (wave-uniform values)
    float bv = sreg[0];
    int   bi = 0;
#pragma unroll
    for (int i = 1; i < C_DIM; ++i) {
        if (sreg[i] > bv) { bv = sreg[i]; bi = i; }
    }
    const int last_tag = __builtin_amdgcn_readfirstlane(bi);

    // prefill tags[t] = last_tag for t in [L, T)
    for (int t = L + tid; t < T_DIM; t += 64) tags[t] = (unsigned char)last_tag;

    // serial backtrace: for t = thi..1: tags[t] = y; y = bp[t][y];  then tags[0] = y
    int y = last_tag;  // wave-uniform
    for (int c0 = (thi >> 6) << 6; c0 >= 0; c0 -= 64) {
        int row[64];   // row[k] holds bp[c0+k][jj] in lane jj
#pragma unroll
        for (int k = 0; k < 64; ++k) row[k] = bp[(c0 + k) * BPS + jj];

        int vacc = 0;
#pragma unroll
        for (int k = 63; k >= 0; --k) {
            const int t = c0 + k;
            vacc = (tid == k) ? y : vacc;                        // tags[t] = y (lane k)
            const int ynew = READLANE_I(row[k], y);
            if ((unsigned)(t - 1) < (unsigned)thi) y = ynew;     // update only for t in [1, thi]
        }
        const int tk = c0 + tid;
        if (tk <= thi) tags[tk] = (unsigned char)(vacc & 0xff);
    }
    __syncthreads();   // phase boundary

    // emit one-hot: 4 rows (t) per iteration, 48 lanes x float4 = 768B coalesced
    if (tid < C_DIM) {
        const int r = tid / 12;          // row-in-group 0..3
        const int q = tid - r * 12;      // float4 slot 0..11
        const int cbase = q * 4;
        float* ob = out + (size_t)b * (T_DIM * C_DIM);
        for (int t0 = 0; t0 < T_DIM; t0 += 4) {
            const unsigned int tg4 = *(const unsigned int*)&tags[t0];
            const int mytag = (int)((tg4 >> (r * 8)) & 0xffu);
            float4 v;
            v.x = (cbase + 0 == mytag) ? 1.0f : 0.0f;
            v.y = (cbase + 1 == mytag) ? 1.0f : 0.0f;
            v.z = (cbase + 2 == mytag) ? 1.0f : 0.0f;
            v.w = (cbase + 3 == mytag) ? 1.0f : 0.0f;
            *(float4*)(ob + (size_t)(t0 + r) * C_DIM + cbase) = v;
        }
    }
}

extern "C" void kernel_launch(void* const* d_in, const int* in_sizes, int n_in,
                              void* d_out, int out_size, void* d_ws, size_t ws_size,
                              hipStream_t stream) {
    const float* pot    = (const float*)d_in[0];
    const int*   sl     = (const int*)d_in[1];
    const float* trans  = (const float*)d_in[2];
    float*       out    = (float*)d_out;
    const int B = in_sizes[1];  // sequence_lengths has B elements
    crf_viterbi<<<B, 64, 0, stream>>>(pot, sl, trans, out);
}

// Round 9
// 371.738 us; speedup vs baseline: 1.1777x; 1.0673x over previous
//
#include <hip/hip_runtime.h>

#define T_DIM 512
#define C_DIM 48
#define BPS   64          // bp row stride (padded to 64 so all lanes store)
#define CH    4           // global-prefetch chunk (distance ~4-8 steps)

typedef float f32x2 __attribute__((ext_vector_type(2)));
typedef float f32x4 __attribute__((ext_vector_type(4)));

#if __has_builtin(__builtin_amdgcn_readlane)
#define READLANE_I(v, l) __builtin_amdgcn_readlane((v), (l))
#else
#define READLANE_I(v, l) __shfl((v), (l), 64)
#endif

// Compiler-level ordering fence for single-wave LDS communication.
// DS ops from one wave execute in order; we only need to stop the compiler
// from reordering/caching across the step boundary. (Validated R3: absmax=0.)
#if __has_builtin(__builtin_amdgcn_wave_barrier)
#define WAVE_SYNC() do { __asm__ __volatile__("" ::: "memory"); __builtin_amdgcn_wave_barrier(); } while (0)
#else
#define WAVE_SYNC() __asm__ __volatile__("" ::: "memory")
#endif

__device__ __forceinline__ unsigned umin_(unsigned a, unsigned b) { return a < b ? a : b; }

#define MAX3(a, b, c) fmaxf(fmaxf((a), (b)), (c))
#define CV(I_)  (cv2[(I_) / 2][(I_) & 1])
// d = cv_i - m is +0.0 (bits 0) iff cv_i == m, else negative (bits >= 0x80000000).
// bits(d)|i == i for max-tier, huge otherwise; umin -> lowest max-tier index
// == jnp.argmax first-occurrence tie-break, exactly. (Validated R8: absmax=0.)
#define UU(I_)  (__float_as_uint(d2[(I_) / 2][(I_) & 1]) | (unsigned)(I_))
#define EMIN3(I_) umin_(umin_(UU(I_), UU((I_) + 1)), UU((I_) + 2))

// One Viterbi step. Scores wave-uniform in LDS sc[cur][0..47]; lane j computes
// argmax_i(s_i + tc_i[j]). Packed fp32 (v_pk_add_f32) for the adds/subs,
// v_max3_f32 value tree, 1-op-encode + v_min3_u32 index tree.
// Broadcast back via single ds_write_b32 (in-order DS, single wave).
#define VSTEP(T_, PV_) do {                                                  \
    const f32x4* sp_ = (const f32x4*)sc[cur];                                \
    f32x2 cv2[24];                                                           \
    _Pragma("unroll")                                                        \
    for (int m_ = 0; m_ < 12; ++m_) {                                        \
        f32x4 sv_ = sp_[m_];                                                 \
        cv2[2 * m_]     = sv_.xy + tc2[2 * m_];                              \
        cv2[2 * m_ + 1] = sv_.zw + tc2[2 * m_ + 1];                          \
    }                                                                        \
    float A0  = MAX3(CV(0),  CV(1),  CV(2));                                 \
    float A1  = MAX3(CV(3),  CV(4),  CV(5));                                 \
    float A2  = MAX3(CV(6),  CV(7),  CV(8));                                 \
    float A3  = MAX3(CV(9),  CV(10), CV(11));                                \
    float A4  = MAX3(CV(12), CV(13), CV(14));                                \
    float A5  = MAX3(CV(15), CV(16), CV(17));                                \
    float A6  = MAX3(CV(18), CV(19), CV(20));                                \
    float A7  = MAX3(CV(21), CV(22), CV(23));                                \
    float A8  = MAX3(CV(24), CV(25), CV(26));                                \
    float A9  = MAX3(CV(27), CV(28), CV(29));                                \
    float A10 = MAX3(CV(30), CV(31), CV(32));                                \
    float A11 = MAX3(CV(33), CV(34), CV(35));                                \
    float A12 = MAX3(CV(36), CV(37), CV(38));                                \
    float A13 = MAX3(CV(39), CV(40), CV(41));                                \
    float A14 = MAX3(CV(42), CV(43), CV(44));                                \
    float A15 = MAX3(CV(45), CV(46), CV(47));                                \
    float B0 = MAX3(A0,  A1,  A2);                                           \
    float B1 = MAX3(A3,  A4,  A5);                                           \
    float B2 = MAX3(A6,  A7,  A8);                                           \
    float B3 = MAX3(A9,  A10, A11);                                          \
    float B4 = MAX3(A12, A13, A14);                                          \
    float Cx0 = MAX3(B0, B1, B2);                                            \
    float Cx1 = MAX3(B3, B4, A15);                                           \
    const float m_v = fmaxf(Cx0, Cx1);                                       \
    f32x2 d2[24];                                                            \
    _Pragma("unroll")                                                        \
    for (int k_ = 0; k_ < 24; ++k_) d2[k_] = cv2[k_] - m_v;  /* pk sub */    \
    unsigned U0  = EMIN3(0);   unsigned U1  = EMIN3(3);                      \
    unsigned U2  = EMIN3(6);   unsigned U3  = EMIN3(9);                      \
    unsigned U4  = EMIN3(12);  unsigned U5  = EMIN3(15);                     \
    unsigned U6  = EMIN3(18);  unsigned U7  = EMIN3(21);                     \
    unsigned U8  = EMIN3(24);  unsigned U9  = EMIN3(27);                     \
    unsigned U10 = EMIN3(30);  unsigned U11 = EMIN3(33);                     \
    unsigned U12 = EMIN3(36);  unsigned U13 = EMIN3(39);                     \
    unsigned U14 = EMIN3(42);  unsigned U15 = EMIN3(45);                     \
    unsigned V0 = umin_(umin_(U0,  U1),  U2);                                \
    unsigned V1 = umin_(umin_(U3,  U4),  U5);                                \
    unsigned V2 = umin_(umin_(U6,  U7),  U8);                                \
    unsigned V3 = umin_(umin_(U9,  U10), U11);                               \
    unsigned V4 = umin_(umin_(U12, U13), U14);                               \
    unsigned W0 = umin_(umin_(V0, V1), V2);                                  \
    unsigned W1 = umin_(umin_(V3, V4), U15);                                 \
    const unsigned wi_ = umin_(W0, W1);                                      \
    const float ns_ = m_v + (PV_);                                           \
    const int nxt_ = cur ^ 1;                                                \
    bp[(T_) * BPS + tid] = (unsigned char)wi_;  /* all 64 lanes; pad ok */   \
    sc[nxt_][tid] = ns_;                        /* lanes 48-63 hit pad */    \
    cur = nxt_;                                                              \
    WAVE_SYNC();                                                             \
} while (0)

__global__ __launch_bounds__(64) void crf_viterbi(
    const float* __restrict__ pot,     // [B][T][C]
    const int*   __restrict__ seqlen,  // [B][1]
    const float* __restrict__ trans,   // [C][C]
    float*       __restrict__ out)     // [B][T][C] one-hot f32
{
    const int b   = blockIdx.x;
    const int tid = threadIdx.x;
    const int jj  = (tid < C_DIM) ? tid : (C_DIM - 1);  // clamped for safe loads

    __shared__ __align__(16) float sc[2][64];            // padded to 64 lanes
    __shared__ unsigned char bp[T_DIM * BPS];            // rows 1..L-1 used
    __shared__ __align__(4) unsigned char tags[T_DIM];

    const float* potb = pot + (size_t)b * (T_DIM * C_DIM);
    const int L   = seqlen[b];          // in [1, 511]
    const int thi = L - 1;

    // transitions column j as 24 packed pairs (clamped col for lanes >= 48)
    f32x2 tc2[24];
#pragma unroll
    for (int k = 0; k < 24; ++k) {
        tc2[k][0] = trans[(2 * k)     * C_DIM + jj];
        tc2[k][1] = trans[(2 * k + 1) * C_DIM + jj];
    }

    // init: score vector = potentials[:,0] (staged in LDS, wave-uniform reads)
    sc[0][tid] = potb[jj];
    WAVE_SYNC();

    int cur = 0;
    const float* pp = potb + jj;

    // software-pipelined forward loop: prefetch chunk CH ahead (clamped rows)
    float pb[CH];
#pragma unroll
    for (int k = 0; k < CH; ++k) {
        int tt = 1 + k; if (tt > T_DIM - 1) tt = T_DIM - 1;
        pb[k] = pp[tt * C_DIM];
    }
    for (int t0 = 1; t0 < L; t0 += CH) {
        float nb[CH];
#pragma unroll
        for (int k = 0; k < CH; ++k) {
            int tt = t0 + CH + k; if (tt > T_DIM - 1) tt = T_DIM - 1;
            nb[k] = pp[tt * C_DIM];
        }
#pragma unroll
        for (int k = 0; k < CH; ++k) {
            const int t = t0 + k;
            if (t >= L) break;           // wave-uniform branch
            VSTEP(t, pb[k]);
        }
#pragma unroll
        for (int k = 0; k < CH; ++k) pb[k] = nb[k];
    }
    __syncthreads();   // phase boundary (single wave; cheap)

    // last_tag = argmax over final scores (uniform LDS reads, broadcast)
    const float* fs = sc[cur];
    float bv = fs[0];
    int   bi = 0;
#pragma unroll
    for (int i = 1; i < C_DIM; ++i) {
        float v = fs[i];
        if (v > bv) { bv = v; bi = i; }
    }
    const int last_tag = __builtin_amdgcn_readfirstlane(bi);

    // prefill tags[t] = last_tag for t in [L, T)
    for (int t = L + tid; t < T_DIM; t += 64) tags[t] = (unsigned char)last_tag;

    // serial backtrace: for t = thi..1: tags[t] = y; y = bp[t][y];  then tags[0] = y
    int y = last_tag;  // wave-uniform
    for (int c0 = (thi >> 6) << 6; c0 >= 0; c0 -= 64) {
        int row[64];   // row[k] holds bp[c0+k][jj] in lane jj
#pragma unroll
        for (int k = 0; k < 64; ++k) row[k] = bp[(c0 + k) * BPS + jj];

        int vacc = 0;
#pragma unroll
        for (int k = 63; k >= 0; --k) {
            const int t = c0 + k;
            vacc = (tid == k) ? y : vacc;                        // tags[t] = y (lane k)
            const int ynew = READLANE_I(row[k], y);
            if ((unsigned)(t - 1) < (unsigned)thi) y = ynew;     // update only for t in [1, thi]
        }
        const int tk = c0 + tid;
        if (tk <= thi) tags[tk] = (unsigned char)(vacc & 0xff);
    }
    __syncthreads();   // phase boundary

    // emit one-hot: 4 rows (t) per iteration, 48 lanes x float4 = 768B coalesced
    if (tid < C_DIM) {
        const int r = tid / 12;          // row-in-group 0..3
        const int q = tid - r * 12;      // float4 slot 0..11
        const int cbase = q * 4;
        float* ob = out + (size_t)b * (T_DIM * C_DIM);
        for (int t0 = 0; t0 < T_DIM; t0 += 4) {
            const unsigned int tg4 = *(const unsigned int*)&tags[t0];
            const int mytag = (int)((tg4 >> (r * 8)) & 0xffu);
            float4 v;
            v.x = (cbase + 0 == mytag) ? 1.0f : 0.0f;
            v.y = (cbase + 1 == mytag) ? 1.0f : 0.0f;
            v.z = (cbase + 2 == mytag) ? 1.0f : 0.0f;
            v.w = (cbase + 3 == mytag) ? 1.0f : 0.0f;
            *(float4*)(ob + (size_t)(t0 + r) * C_DIM + cbase) = v;
        }
    }
}

extern "C" void kernel_launch(void* const* d_in, const int* in_sizes, int n_in,
                              void* d_out, int out_size, void* d_ws, size_t ws_size,
                              hipStream_t stream) {
    const float* pot    = (const float*)d_in[0];
    const int*   sl     = (const int*)d_in[1];
    const float* trans  = (const float*)d_in[2];
    float*       out    = (float*)d_out;
    const int B = in_sizes[1];  // sequence_lengths has B elements
    crf_viterbi<<<B, 64, 0, stream>>>(pot, sl, trans, out);
}